// Round 1
// baseline (227.393 us; speedup 1.0000x reference)
//
#include <hip/hip_runtime.h>

typedef __bf16 bf16;
typedef bf16 bf16x8 __attribute__((ext_vector_type(8)));
typedef float f32x4 __attribute__((ext_vector_type(4)));
typedef int ivec4 __attribute__((ext_vector_type(4)));

#define PTOT 147456   // 384*384
#define N384 384

static __device__ __forceinline__ f32x4 mfma16(bf16x8 a, bf16x8 b, f32x4 c) {
  return __builtin_amdgcn_mfma_f32_16x16x32_bf16(a, b, c, 0, 0, 0);
}

// ---------------------------------------------------------------------------
// k_prep: transpose 5 weight matrices [128(in)][128(out)] f32 -> [out][in] bf16
// slots: 0=W_a_p 1=W_a_g 2=W_b_p 3=W_b_g 4=W_z
// ---------------------------------------------------------------------------
__global__ __launch_bounds__(256) void k_prep(
    const float* __restrict__ w0, const float* __restrict__ w1,
    const float* __restrict__ w2, const float* __restrict__ w3,
    const float* __restrict__ w4, bf16* __restrict__ wt)
{
  const int m = blockIdx.x;
  const float* src = (m == 0) ? w0 : (m == 1) ? w1 : (m == 2) ? w2 : (m == 3) ? w3 : w4;
  bf16* dst = wt + m * 16384;
  for (int i = threadIdx.x; i < 16384; i += 256) {
    const int r = i >> 7, cc = i & 127;   // dst[r][cc] = src[cc][r]
    dst[i] = (bf16)src[cc * 128 + r];
  }
}

// ---------------------------------------------------------------------------
// k1: LayerNorm + 4 projections (MFMA) + sigmoid gating + mask.
// Block = 256 threads (4 waves), 32 positions. Wave w computes xn @ W[w].
// Outputs a_t[c][p], b_t[c][p] (channel-planar bf16).
// ---------------------------------------------------------------------------
__global__ __launch_bounds__(256) void k1_ln_proj(
    const float* __restrict__ x, const float* __restrict__ mask,
    const float* __restrict__ gamma, const float* __restrict__ beta,
    const float* __restrict__ bap, const float* __restrict__ bbp,
    const bf16* __restrict__ wt,
    bf16* __restrict__ a_t, bf16* __restrict__ b_t)
{
  __shared__ __align__(16) char smem[18432 + 16384 + 128];
  bf16 (*xn)[136] = (bf16(*)[136])smem;            // [32][136] (pad 8 -> 2-way max)
  bf16 (*ot)[36]  = (bf16(*)[36])smem;             // [256][36] overlay (after xn dead)
  bf16 (*gl)[128] = (bf16(*)[128])(smem + 18432);  // [64][128] gates (sel*32+pos)
  float* ml = (float*)(smem + 18432 + 16384);      // [32] mask

  const int t = threadIdx.x;
  const int l = t & 63;
  const int w = t >> 6;
  const int p0 = blockIdx.x << 5;

  if (t < 32) ml[t] = mask[p0 + t];

  // ---- LayerNorm: thread t handles pos=t/8, channels (t&7)*16..+15 ----
  f32x4 v[4];
  const float* xb = x + (size_t)p0 * 128 + t * 16;
  #pragma unroll
  for (int i = 0; i < 4; ++i) v[i] = *(const f32x4*)(xb + i * 4);

  float s = 0.f, s2 = 0.f;
  #pragma unroll
  for (int i = 0; i < 4; ++i)
    #pragma unroll
    for (int j = 0; j < 4; ++j) { const float f = v[i][j]; s += f; s2 += f * f; }
  #pragma unroll
  for (int m = 1; m < 8; m <<= 1) {
    s  += __shfl_xor(s, m, 64);
    s2 += __shfl_xor(s2, m, 64);
  }
  const float mu = s * (1.f / 128.f);
  const float rs = rsqrtf(s2 * (1.f / 128.f) - mu * mu + 1e-5f);

  const int prow = t >> 3;
  const int csub = (t & 7) << 4;
  f32x4 g4[4], bt4[4];
  #pragma unroll
  for (int i = 0; i < 4; ++i) {
    g4[i]  = *(const f32x4*)(gamma + csub + i * 4);
    bt4[i] = *(const f32x4*)(beta  + csub + i * 4);
  }
  bf16x8 xv0, xv1;
  #pragma unroll
  for (int i = 0; i < 4; ++i)
    #pragma unroll
    for (int j = 0; j < 4; ++j) {
      const float f = (v[i][j] - mu) * rs * g4[i][j] + bt4[i][j];
      const int e = i * 4 + j;
      if (e < 8) xv0[e] = (bf16)f; else xv1[e - 8] = (bf16)f;
    }
  *(bf16x8*)&xn[prow][csub]     = xv0;
  *(bf16x8*)&xn[prow][csub + 8] = xv1;
  __syncthreads();

  // ---- MFMA: 32 pos x 128 out, K=128. A: m=l&15, k=(l>>4)*8+j ----
  const int fr = l & 15, fq = l >> 4;
  bf16x8 af[2][4];
  #pragma unroll
  for (int mi = 0; mi < 2; ++mi)
    #pragma unroll
    for (int ks = 0; ks < 4; ++ks)
      af[mi][ks] = *(const bf16x8*)&xn[mi * 16 + fr][ks * 32 + fq * 8];

  const bf16* wm = wt + w * 16384;
  f32x4 acc[2][8];
  #pragma unroll
  for (int mi = 0; mi < 2; ++mi)
    #pragma unroll
    for (int n = 0; n < 8; ++n) acc[mi][n] = (f32x4){0.f, 0.f, 0.f, 0.f};

  #pragma unroll
  for (int n = 0; n < 8; ++n) {
    #pragma unroll
    for (int ks = 0; ks < 4; ++ks) {
      const bf16x8 bfv = *(const bf16x8*)(wm + (size_t)(n * 16 + fr) * 128 + ks * 32 + fq * 8);
      acc[0][n] = mfma16(af[0][ks], bfv, acc[0][n]);
      acc[1][n] = mfma16(af[1][ks], bfv, acc[1][n]);
    }
  }

  // ---- gates (waves 1,3) -> LDS ----
  if (w & 1) {
    const int sel = w >> 1;
    #pragma unroll
    for (int mi = 0; mi < 2; ++mi)
      #pragma unroll
      for (int n = 0; n < 8; ++n)
        #pragma unroll
        for (int r = 0; r < 4; ++r) {
          const int pos = mi * 16 + fq * 4 + r;
          const int ch  = n * 16 + fr;
          const float sg = 1.f / (1.f + __expf(-acc[mi][n][r]));
          gl[sel * 32 + pos][ch] = (bf16)sg;
        }
  }
  __syncthreads();

  // ---- proj waves (0,2): bias, gate, mask -> transposed staging ----
  if (!(w & 1)) {
    const int sel = w >> 1;
    const float* bp = sel ? bbp : bap;
    #pragma unroll
    for (int n = 0; n < 8; ++n) {
      const int ch = n * 16 + fr;
      const float bias = bp[ch];
      #pragma unroll
      for (int mi = 0; mi < 2; ++mi)
        #pragma unroll
        for (int r = 0; r < 4; ++r) {
          const int pos = mi * 16 + fq * 4 + r;
          const float val = (acc[mi][n][r] + bias) * (float)gl[sel * 32 + pos][ch] * ml[pos];
          ot[sel * 128 + ch][pos] = (bf16)val;
        }
    }
  }
  __syncthreads();

  // ---- coalesced channel-planar store ----
  #pragma unroll
  for (int rep = 0; rep < 16; ++rep) {
    const int f = rep * 256 + t;
    const int ch = f >> 5, pp = f & 31;
    const size_t gidx = (size_t)ch * PTOT + p0 + pp;
    a_t[gidx] = ot[ch][pp];
    b_t[gidx] = ot[128 + ch][pp];
  }
}

// ---------------------------------------------------------------------------
// k2: per-channel GEMM O_c = A_c(384x384) * B_c(384x384), 128x128 tile, BK=32.
// grid (9 tiles, 128 channels), 4 waves each own a 64x64 quadrant.
// ---------------------------------------------------------------------------
__global__ __launch_bounds__(256) void k2_tri(
    const bf16* __restrict__ a_t, const bf16* __restrict__ b_t, bf16* __restrict__ o_t)
{
  __shared__ __align__(16) bf16 As[128][40];   // [i][k], pad -> conflict-free frags
  __shared__ __align__(16) bf16 Bt[128][40];   // [j][k] (B transposed)
  const int t = threadIdx.x, l = t & 63, w = t >> 6;
  const int fr = l & 15, fq = l >> 4;
  const int ti = blockIdx.x;                   // 0..8
  const int c  = blockIdx.y;                   // channel
  const int i0 = (ti / 3) * 128, j0 = (ti % 3) * 128;
  const bf16* ap = a_t + (size_t)c * PTOT;
  const bf16* bp = b_t + (size_t)c * PTOT;
  const int wm = (w >> 1) * 64, wn = (w & 1) * 64;
  const int arow = t >> 2, aseg = t & 3;       // A staging
  const int bj = t & 127, bkh = (t >> 7) * 16; // B staging (transpose via registers)

  f32x4 acc[4][4];
  #pragma unroll
  for (int mi = 0; mi < 4; ++mi)
    #pragma unroll
    for (int ni = 0; ni < 4; ++ni) acc[mi][ni] = (f32x4){0.f, 0.f, 0.f, 0.f};

  for (int kt = 0; kt < 12; ++kt) {
    const int k0 = kt * 32;
    __syncthreads();
    // stage A [128][32]: rows contiguous in k
    #pragma unroll
    for (int rep = 0; rep < 2; ++rep) {
      const int row = arow + rep * 64;
      *(ivec4*)&As[row][aseg * 8] =
          *(const ivec4*)(ap + (size_t)(i0 + row) * N384 + k0 + aseg * 8);
    }
    // stage B^T [128][32]: strided-coalesced global reads (2B/lane, 128B/wave)
    bf16 rb[16] __attribute__((aligned(16)));
    #pragma unroll
    for (int kk = 0; kk < 16; ++kk)
      rb[kk] = bp[(size_t)(k0 + bkh + kk) * N384 + j0 + bj];
    *(ivec4*)&Bt[bj][bkh]     = *(const ivec4*)&rb[0];
    *(ivec4*)&Bt[bj][bkh + 8] = *(const ivec4*)&rb[8];
    __syncthreads();

    bf16x8 af[4], bfv[4];
    #pragma unroll
    for (int mi = 0; mi < 4; ++mi)
      af[mi] = *(const bf16x8*)&As[wm + mi * 16 + fr][fq * 8];
    #pragma unroll
    for (int ni = 0; ni < 4; ++ni)
      bfv[ni] = *(const bf16x8*)&Bt[wn + ni * 16 + fr][fq * 8];
    #pragma unroll
    for (int mi = 0; mi < 4; ++mi)
      #pragma unroll
      for (int ni = 0; ni < 4; ++ni)
        acc[mi][ni] = mfma16(af[mi], bfv[ni], acc[mi][ni]);
  }

  bf16* op = o_t + (size_t)c * PTOT;
  #pragma unroll
  for (int mi = 0; mi < 4; ++mi)
    #pragma unroll
    for (int ni = 0; ni < 4; ++ni)
      #pragma unroll
      for (int r = 0; r < 4; ++r) {
        const int row = i0 + wm + mi * 16 + fq * 4 + r;
        const int col = j0 + wn + ni * 16 + fr;
        op[(size_t)row * N384 + col] = (bf16)acc[mi][ni][r];
      }
}

// ---------------------------------------------------------------------------
// k3: out = x + (o @ W_z + b_z). 64 positions/block, transpose-stage o.
// ---------------------------------------------------------------------------
__global__ __launch_bounds__(256) void k3_out(
    const bf16* __restrict__ o_t, const bf16* __restrict__ wtz,
    const float* __restrict__ x, const float* __restrict__ bz,
    float* __restrict__ out)
{
  __shared__ __align__(16) bf16 Ao[64][136];
  const int t = threadIdx.x, l = t & 63, w = t >> 6;
  const int fr = l & 15, fq = l >> 4;
  const int p0 = blockIdx.x << 6;
  const int pos = t & 63, chh = (t >> 6) * 32;

  bf16 rb[32] __attribute__((aligned(16)));
  #pragma unroll
  for (int cc = 0; cc < 32; ++cc)
    rb[cc] = o_t[(size_t)(chh + cc) * PTOT + p0 + pos];
  #pragma unroll
  for (int q = 0; q < 4; ++q)
    *(ivec4*)&Ao[pos][chh + q * 8] = *(const ivec4*)&rb[q * 8];
  __syncthreads();

  bf16x8 af[4];
  #pragma unroll
  for (int ks = 0; ks < 4; ++ks)
    af[ks] = *(const bf16x8*)&Ao[w * 16 + fr][ks * 32 + fq * 8];

  f32x4 acc[8];
  #pragma unroll
  for (int n = 0; n < 8; ++n) acc[n] = (f32x4){0.f, 0.f, 0.f, 0.f};
  #pragma unroll
  for (int n = 0; n < 8; ++n)
    #pragma unroll
    for (int ks = 0; ks < 4; ++ks) {
      const bf16x8 bfv = *(const bf16x8*)(wtz + (size_t)(n * 16 + fr) * 128 + ks * 32 + fq * 8);
      acc[n] = mfma16(af[ks], bfv, acc[n]);
    }

  #pragma unroll
  for (int n = 0; n < 8; ++n) {
    const int ch = n * 16 + fr;
    const float bias = bz[ch];
    #pragma unroll
    for (int r = 0; r < 4; ++r) {
      const int pp = p0 + w * 16 + fq * 4 + r;
      const size_t idx = (size_t)pp * 128 + ch;
      out[idx] = x[idx] + acc[n][r] + bias;
    }
  }
}

// ---------------------------------------------------------------------------
extern "C" void kernel_launch(void* const* d_in, const int* in_sizes, int n_in,
                              void* d_out, int out_size, void* d_ws, size_t ws_size,
                              hipStream_t stream) {
  const float* x     = (const float*)d_in[0];
  const float* mask  = (const float*)d_in[1];
  const float* gamma = (const float*)d_in[2];
  const float* beta  = (const float*)d_in[3];
  const float* Wap   = (const float*)d_in[4];
  const float* bap   = (const float*)d_in[5];
  const float* Wag   = (const float*)d_in[6];
  const float* Wbp   = (const float*)d_in[7];
  const float* bbp   = (const float*)d_in[8];
  const float* Wbg   = (const float*)d_in[9];
  const float* Wz    = (const float*)d_in[10];
  const float* bz    = (const float*)d_in[11];

  char* ws = (char*)d_ws;
  bf16* wt  = (bf16*)ws;                         // 5*128*128 bf16 = 160KB
  bf16* a_t = (bf16*)(ws + 163840);              // [128][147456] bf16
  bf16* b_t = a_t + (size_t)128 * PTOT;
  bf16* o_t = b_t + (size_t)128 * PTOT;
  float* out = (float*)d_out;

  k_prep<<<5, 256, 0, stream>>>(Wap, Wag, Wbp, Wbg, Wz, wt);
  k1_ln_proj<<<4608, 256, 0, stream>>>(x, mask, gamma, beta, bap, bbp, wt, a_t, b_t);
  k2_tri<<<dim3(9, 128), 256, 0, stream>>>(a_t, b_t, o_t);
  k3_out<<<2304, 256, 0, stream>>>(o_t, wt + 4 * 16384, x, bz, out);
}

// Round 2
// 206.058 us; speedup vs baseline: 1.1035x; 1.1035x over previous
//
#include <hip/hip_runtime.h>

typedef __bf16 bf16;
typedef bf16 bf16x4 __attribute__((ext_vector_type(4)));
typedef bf16 bf16x8 __attribute__((ext_vector_type(8)));
typedef float f32x4 __attribute__((ext_vector_type(4)));
typedef int ivec4 __attribute__((ext_vector_type(4)));

#define PTOT 147456   // 384*384
#define N384 384

static __device__ __forceinline__ f32x4 mfma16(bf16x8 a, bf16x8 b, f32x4 c) {
  return __builtin_amdgcn_mfma_f32_16x16x32_bf16(a, b, c, 0, 0, 0);
}

// ---------------------------------------------------------------------------
// k_prep: transpose 5 weight matrices [128(in)][128(out)] f32 -> [out][in] bf16
// slots: 0=W_a_p 1=W_a_g 2=W_b_p 3=W_b_g 4=W_z
// ---------------------------------------------------------------------------
__global__ __launch_bounds__(256) void k_prep(
    const float* __restrict__ w0, const float* __restrict__ w1,
    const float* __restrict__ w2, const float* __restrict__ w3,
    const float* __restrict__ w4, bf16* __restrict__ wt)
{
  const int m = blockIdx.x;
  const float* src = (m == 0) ? w0 : (m == 1) ? w1 : (m == 2) ? w2 : (m == 3) ? w3 : w4;
  bf16* dst = wt + m * 16384;
  for (int i = threadIdx.x; i < 16384; i += 256) {
    const int r = i >> 7, cc = i & 127;   // dst[r][cc] = src[cc][r]
    dst[i] = (bf16)src[cc * 128 + r];
  }
}

// ---------------------------------------------------------------------------
// k1 v2: LayerNorm + 4 projections + register-local sigmoid gating + mask.
// Block 256 = 4 waves, 64 positions. Wave w: pair=(w>>1) (a or b),
// pos-half=(w&1) (32 pos), all 128 channels. Gate exchange in registers.
// Output a_t[c][p], b_t[c][p] via packed 8B stores.
// ---------------------------------------------------------------------------
__global__ __launch_bounds__(256) void k1_ln_proj(
    const float* __restrict__ x, const float* __restrict__ mask,
    const float* __restrict__ gamma, const float* __restrict__ beta,
    const float* __restrict__ bap, const float* __restrict__ bbp,
    const bf16* __restrict__ wt,
    bf16* __restrict__ a_t, bf16* __restrict__ b_t)
{
  __shared__ __align__(16) bf16 xn[64][136];   // pad 8 -> 2-way max on frag reads
  __shared__ float ml[64];

  const int t = threadIdx.x;
  const int l = t & 63;
  const int w = t >> 6;
  const int p0 = blockIdx.x << 6;

  if (t < 64) ml[t] = mask[p0 + t];

  // ---- LayerNorm: 2 rounds x 32 rows; thread -> row (t>>3), 16 channels ----
  const int csub = (t & 7) << 4;
  f32x4 g4[4], bt4[4];
  #pragma unroll
  for (int i = 0; i < 4; ++i) {
    g4[i]  = *(const f32x4*)(gamma + csub + i * 4);
    bt4[i] = *(const f32x4*)(beta  + csub + i * 4);
  }
  #pragma unroll
  for (int it = 0; it < 2; ++it) {
    const int row = (t >> 3) + it * 32;
    f32x4 v[4];
    const float* xb = x + (size_t)(p0 + row) * 128 + csub;
    #pragma unroll
    for (int i = 0; i < 4; ++i) v[i] = *(const f32x4*)(xb + i * 4);

    float s = 0.f, s2 = 0.f;
    #pragma unroll
    for (int i = 0; i < 4; ++i)
      #pragma unroll
      for (int j = 0; j < 4; ++j) { const float f = v[i][j]; s += f; s2 += f * f; }
    #pragma unroll
    for (int m = 1; m < 8; m <<= 1) {
      s  += __shfl_xor(s, m, 64);
      s2 += __shfl_xor(s2, m, 64);
    }
    const float mu = s * (1.f / 128.f);
    const float rs = rsqrtf(s2 * (1.f / 128.f) - mu * mu + 1e-5f);

    bf16x8 xv0, xv1;
    #pragma unroll
    for (int i = 0; i < 4; ++i)
      #pragma unroll
      for (int j = 0; j < 4; ++j) {
        const float f = (v[i][j] - mu) * rs * g4[i][j] + bt4[i][j];
        const int e = i * 4 + j;
        if (e < 8) xv0[e] = (bf16)f; else xv1[e - 8] = (bf16)f;
      }
    *(bf16x8*)&xn[row][csub]     = xv0;
    *(bf16x8*)&xn[row][csub + 8] = xv1;
  }
  __syncthreads();

  // ---- per-wave MFMA: 32 pos x 128 ch x {proj, gate} ----
  const int fr = l & 15, fq = l >> 4;
  const int pair = w >> 1;
  const int prow0 = (w & 1) * 32;

  bf16x8 af[2][4];
  #pragma unroll
  for (int mi = 0; mi < 2; ++mi)
    #pragma unroll
    for (int ks = 0; ks < 4; ++ks)
      af[mi][ks] = *(const bf16x8*)&xn[prow0 + mi * 16 + fr][ks * 32 + fq * 8];

  const bf16* wp = wt + (pair * 2) * 16384;       // proj weights [ch][k]
  const bf16* wg = wt + (pair * 2 + 1) * 16384;   // gate weights [ch][k]
  const float* bp = pair ? bbp : bap;
  bf16* dst = pair ? b_t : a_t;

  #pragma unroll
  for (int nc = 0; nc < 2; ++nc) {
    // gate accumulators for 4 channel-tiles
    f32x4 aG[2][4];
    #pragma unroll
    for (int mi = 0; mi < 2; ++mi)
      #pragma unroll
      for (int n = 0; n < 4; ++n) aG[mi][n] = (f32x4){0.f, 0.f, 0.f, 0.f};
    #pragma unroll
    for (int n = 0; n < 4; ++n)
      #pragma unroll
      for (int ks = 0; ks < 4; ++ks) {
        const bf16x8 bv = *(const bf16x8*)(wg + (size_t)((nc * 4 + n) * 16 + fr) * 128 + ks * 32 + fq * 8);
        aG[0][n] = mfma16(af[0][ks], bv, aG[0][n]);
        aG[1][n] = mfma16(af[1][ks], bv, aG[1][n]);
      }
    #pragma unroll
    for (int n = 0; n < 4; ++n) {
      const int ch = (nc * 4 + n) * 16 + fr;
      const float bias = bp[ch];
      f32x4 aP[2];
      aP[0] = (f32x4){0.f, 0.f, 0.f, 0.f};
      aP[1] = (f32x4){0.f, 0.f, 0.f, 0.f};
      #pragma unroll
      for (int ks = 0; ks < 4; ++ks) {
        const bf16x8 bv = *(const bf16x8*)(wp + (size_t)ch * 128 + ks * 32 + fq * 8);
        aP[0] = mfma16(af[0][ks], bv, aP[0]);
        aP[1] = mfma16(af[1][ks], bv, aP[1]);
      }
      #pragma unroll
      for (int mi = 0; mi < 2; ++mi) {
        const int pb = prow0 + mi * 16 + fq * 4;
        const f32x4 m4 = *(const f32x4*)&ml[pb];
        bf16x4 pk;
        #pragma unroll
        for (int r = 0; r < 4; ++r) {
          const float sg = 1.f / (1.f + __expf(-aG[mi][n][r]));
          pk[r] = (bf16)((aP[mi][r] + bias) * sg * m4[r]);
        }
        *(bf16x4*)(dst + (size_t)ch * PTOT + p0 + pb) = pk;
      }
    }
  }
}

// ---------------------------------------------------------------------------
// k2: per-channel GEMM O_c = A_c(384x384) * B_c(384x384), 128x128 tile, BK=32.
// grid (9 tiles, 128 channels), 4 waves each own a 64x64 quadrant.
// Swapped-operand MFMA -> packed 8B stores along j.
// ---------------------------------------------------------------------------
__global__ __launch_bounds__(256) void k2_tri(
    const bf16* __restrict__ a_t, const bf16* __restrict__ b_t, bf16* __restrict__ o_t)
{
  __shared__ __align__(16) bf16 As[128][40];   // [i][k]
  __shared__ __align__(16) bf16 Bt[128][40];   // [j][k] (B transposed)
  const int t = threadIdx.x, l = t & 63, w = t >> 6;
  const int fr = l & 15, fq = l >> 4;
  const int ti = blockIdx.x;                   // 0..8
  const int c  = blockIdx.y;                   // channel
  const int i0 = (ti / 3) * 128, j0 = (ti % 3) * 128;
  const bf16* ap = a_t + (size_t)c * PTOT;
  const bf16* bp = b_t + (size_t)c * PTOT;
  const int wm = (w >> 1) * 64, wn = (w & 1) * 64;
  const int arow = t >> 2, aseg = t & 3;       // A staging
  const int bj = t & 127, bkh = (t >> 7) * 16; // B staging (transpose via registers)

  f32x4 acc[4][4];
  #pragma unroll
  for (int mi = 0; mi < 4; ++mi)
    #pragma unroll
    for (int ni = 0; ni < 4; ++ni) acc[mi][ni] = (f32x4){0.f, 0.f, 0.f, 0.f};

  for (int kt = 0; kt < 12; ++kt) {
    const int k0 = kt * 32;
    __syncthreads();
    // stage A [128][32]: rows contiguous in k
    #pragma unroll
    for (int rep = 0; rep < 2; ++rep) {
      const int row = arow + rep * 64;
      *(ivec4*)&As[row][aseg * 8] =
          *(const ivec4*)(ap + (size_t)(i0 + row) * N384 + k0 + aseg * 8);
    }
    // stage B^T [128][32]: strided-coalesced global reads (2B/lane, 128B/wave)
    bf16 rb[16] __attribute__((aligned(16)));
    #pragma unroll
    for (int kk = 0; kk < 16; ++kk)
      rb[kk] = bp[(size_t)(k0 + bkh + kk) * N384 + j0 + bj];
    *(ivec4*)&Bt[bj][bkh]     = *(const ivec4*)&rb[0];
    *(ivec4*)&Bt[bj][bkh + 8] = *(const ivec4*)&rb[8];
    __syncthreads();

    bf16x8 af[4], bfv[4];
    #pragma unroll
    for (int mi = 0; mi < 4; ++mi)
      af[mi] = *(const bf16x8*)&As[wm + mi * 16 + fr][fq * 8];
    #pragma unroll
    for (int ni = 0; ni < 4; ++ni)
      bfv[ni] = *(const bf16x8*)&Bt[wn + ni * 16 + fr][fq * 8];
    // swapped operands: D[jm][im] -> lane holds 4 consecutive j per (mi,ni)
    #pragma unroll
    for (int mi = 0; mi < 4; ++mi)
      #pragma unroll
      for (int ni = 0; ni < 4; ++ni)
        acc[mi][ni] = mfma16(bfv[ni], af[mi], acc[mi][ni]);
  }

  bf16* op = o_t + (size_t)c * PTOT;
  #pragma unroll
  for (int mi = 0; mi < 4; ++mi) {
    const int irow = i0 + wm + mi * 16 + fr;
    #pragma unroll
    for (int ni = 0; ni < 4; ++ni) {
      const int jcol = j0 + wn + ni * 16 + fq * 4;
      bf16x4 pk;
      #pragma unroll
      for (int r = 0; r < 4; ++r) pk[r] = (bf16)acc[mi][ni][r];
      *(bf16x4*)(op + (size_t)irow * N384 + jcol) = pk;
    }
  }
}

// ---------------------------------------------------------------------------
// k3: out = x + (o @ W_z + b_z). 64 positions/block, transpose-stage o.
// Swapped-operand MFMA -> f32x4 stores/reads along channel.
// ---------------------------------------------------------------------------
__global__ __launch_bounds__(256) void k3_out(
    const bf16* __restrict__ o_t, const bf16* __restrict__ wtz,
    const float* __restrict__ x, const float* __restrict__ bz,
    float* __restrict__ out)
{
  __shared__ __align__(16) bf16 Ao[64][136];
  const int t = threadIdx.x, l = t & 63, w = t >> 6;
  const int fr = l & 15, fq = l >> 4;
  const int p0 = blockIdx.x << 6;
  const int pos = t & 63, chh = (t >> 6) * 32;

  bf16 rb[32] __attribute__((aligned(16)));
  #pragma unroll
  for (int cc = 0; cc < 32; ++cc)
    rb[cc] = o_t[(size_t)(chh + cc) * PTOT + p0 + pos];
  #pragma unroll
  for (int q = 0; q < 4; ++q)
    *(ivec4*)&Ao[pos][chh + q * 8] = *(const ivec4*)&rb[q * 8];
  __syncthreads();

  bf16x8 af[4];
  #pragma unroll
  for (int ks = 0; ks < 4; ++ks)
    af[ks] = *(const bf16x8*)&Ao[w * 16 + fr][ks * 32 + fq * 8];

  f32x4 acc[8];
  #pragma unroll
  for (int n = 0; n < 8; ++n) acc[n] = (f32x4){0.f, 0.f, 0.f, 0.f};
  #pragma unroll
  for (int n = 0; n < 8; ++n)
    #pragma unroll
    for (int ks = 0; ks < 4; ++ks) {
      const bf16x8 bfv = *(const bf16x8*)(wtz + (size_t)(n * 16 + fr) * 128 + ks * 32 + fq * 8);
      // swapped: D rows = ch (wz m), cols = pos (af m)
      acc[n] = mfma16(bfv, af[ks], acc[n]);
    }

  const int pp = p0 + w * 16 + fr;
  #pragma unroll
  for (int n = 0; n < 8; ++n) {
    const int ch = n * 16 + fq * 4;
    const f32x4 b4 = *(const f32x4*)(bz + ch);
    const size_t idx = (size_t)pp * 128 + ch;
    const f32x4 x4 = *(const f32x4*)(x + idx);
    f32x4 o4;
    #pragma unroll
    for (int r = 0; r < 4; ++r) o4[r] = x4[r] + acc[n][r] + b4[r];
    *(f32x4*)(out + idx) = o4;
  }
}

// ---------------------------------------------------------------------------
extern "C" void kernel_launch(void* const* d_in, const int* in_sizes, int n_in,
                              void* d_out, int out_size, void* d_ws, size_t ws_size,
                              hipStream_t stream) {
  const float* x     = (const float*)d_in[0];
  const float* mask  = (const float*)d_in[1];
  const float* gamma = (const float*)d_in[2];
  const float* beta  = (const float*)d_in[3];
  const float* Wap   = (const float*)d_in[4];
  const float* bap   = (const float*)d_in[5];
  const float* Wag   = (const float*)d_in[6];
  const float* Wbp   = (const float*)d_in[7];
  const float* bbp   = (const float*)d_in[8];
  const float* Wbg   = (const float*)d_in[9];
  const float* Wz    = (const float*)d_in[10];
  const float* bz    = (const float*)d_in[11];

  char* ws = (char*)d_ws;
  bf16* wt  = (bf16*)ws;                         // 5*128*128 bf16 = 160KB
  bf16* a_t = (bf16*)(ws + 163840);              // [128][147456] bf16
  bf16* b_t = a_t + (size_t)128 * PTOT;
  bf16* o_t = b_t + (size_t)128 * PTOT;
  float* out = (float*)d_out;

  k_prep<<<5, 256, 0, stream>>>(Wap, Wag, Wbp, Wbg, Wz, wt);
  k1_ln_proj<<<2304, 256, 0, stream>>>(x, mask, gamma, beta, bap, bbp, wt, a_t, b_t);
  k2_tri<<<dim3(9, 128), 256, 0, stream>>>(a_t, b_t, o_t);
  k3_out<<<2304, 256, 0, stream>>>(o_t, wt + 4 * 16384, x, bz, out);
}

// Round 3
// 163.503 us; speedup vs baseline: 1.3908x; 1.2603x over previous
//
#include <hip/hip_runtime.h>

typedef __bf16 bf16;
typedef bf16 bf16x4 __attribute__((ext_vector_type(4)));
typedef bf16 bf16x8 __attribute__((ext_vector_type(8)));
typedef float f32x4 __attribute__((ext_vector_type(4)));
typedef int ivec4 __attribute__((ext_vector_type(4)));

#define PTOT 147456   // 384*384
#define N384 384

static __device__ __forceinline__ f32x4 mfma16(bf16x8 a, bf16x8 b, f32x4 c) {
  return __builtin_amdgcn_mfma_f32_16x16x32_bf16(a, b, c, 0, 0, 0);
}

// ---------------------------------------------------------------------------
// k_prep: repack 5 weight matrices [128(in)][128(out)] f32 into per-lane MFMA
// fragment order (bf16): wf[m][ ((n*4+ks)*64 + lane)*8 + e ] =
//   W[k = ks*32 + (lane>>4)*8 + e][ch = n*16 + (lane&15)]
// so a wave's fragment load is one contiguous 1KB transaction.
// slots: 0=W_a_p 1=W_a_g 2=W_b_p 3=W_b_g 4=W_z
// ---------------------------------------------------------------------------
__global__ __launch_bounds__(256) void k_prep(
    const float* __restrict__ w0, const float* __restrict__ w1,
    const float* __restrict__ w2, const float* __restrict__ w3,
    const float* __restrict__ w4, bf16* __restrict__ wt)
{
  const int m = blockIdx.x;
  const float* src = (m == 0) ? w0 : (m == 1) ? w1 : (m == 2) ? w2 : (m == 3) ? w3 : w4;
  bf16* dst = wt + m * 16384;
  for (int slot = threadIdx.x; slot < 2048; slot += 256) {
    const int l  = slot & 63;
    const int ks = (slot >> 6) & 3;
    const int n  = slot >> 8;
    const int ch = n * 16 + (l & 15);
    const int kb = ks * 32 + (l >> 4) * 8;
    bf16 tmp[8] __attribute__((aligned(16)));
    #pragma unroll
    for (int e = 0; e < 8; ++e)
      tmp[e] = (bf16)src[(size_t)(kb + e) * 128 + ch];
    *(ivec4*)(dst + slot * 8) = *(const ivec4*)tmp;
  }
}

// ---------------------------------------------------------------------------
// k1 v3: LayerNorm + 4 projections + register-local sigmoid gating + mask.
// Block 256 = 4 waves, 64 positions. Wave w: pair=(w>>1) (a or b),
// pos-half=(w&1). Weights read in fragment order (coalesced 1KB loads).
// Output a_t[c][p], b_t[c][p] via packed 8B stores.
// ---------------------------------------------------------------------------
__global__ __launch_bounds__(256) void k1_ln_proj(
    const float* __restrict__ x, const float* __restrict__ mask,
    const float* __restrict__ gamma, const float* __restrict__ beta,
    const float* __restrict__ bap, const float* __restrict__ bbp,
    const bf16* __restrict__ wt,
    bf16* __restrict__ a_t, bf16* __restrict__ b_t)
{
  __shared__ __align__(16) bf16 xn[64][136];   // pad 8
  __shared__ float ml[64];

  const int t = threadIdx.x;
  const int l = t & 63;
  const int w = t >> 6;
  const int p0 = blockIdx.x << 6;

  if (t < 64) ml[t] = mask[p0 + t];

  // ---- LayerNorm: 2 rounds x 32 rows; thread -> row (t>>3), 16 channels ----
  const int csub = (t & 7) << 4;
  f32x4 g4[4], bt4[4];
  #pragma unroll
  for (int i = 0; i < 4; ++i) {
    g4[i]  = *(const f32x4*)(gamma + csub + i * 4);
    bt4[i] = *(const f32x4*)(beta  + csub + i * 4);
  }
  #pragma unroll
  for (int it = 0; it < 2; ++it) {
    const int row = (t >> 3) + it * 32;
    f32x4 v[4];
    const float* xb = x + (size_t)(p0 + row) * 128 + csub;
    #pragma unroll
    for (int i = 0; i < 4; ++i) v[i] = *(const f32x4*)(xb + i * 4);

    float s = 0.f, s2 = 0.f;
    #pragma unroll
    for (int i = 0; i < 4; ++i)
      #pragma unroll
      for (int j = 0; j < 4; ++j) { const float f = v[i][j]; s += f; s2 += f * f; }
    #pragma unroll
    for (int m = 1; m < 8; m <<= 1) {
      s  += __shfl_xor(s, m, 64);
      s2 += __shfl_xor(s2, m, 64);
    }
    const float mu = s * (1.f / 128.f);
    const float rs = rsqrtf(s2 * (1.f / 128.f) - mu * mu + 1e-5f);

    bf16x8 xv0, xv1;
    #pragma unroll
    for (int i = 0; i < 4; ++i)
      #pragma unroll
      for (int j = 0; j < 4; ++j) {
        const float f = (v[i][j] - mu) * rs * g4[i][j] + bt4[i][j];
        const int e = i * 4 + j;
        if (e < 8) xv0[e] = (bf16)f; else xv1[e - 8] = (bf16)f;
      }
    *(bf16x8*)&xn[row][csub]     = xv0;
    *(bf16x8*)&xn[row][csub + 8] = xv1;
  }
  __syncthreads();

  // ---- per-wave MFMA: 32 pos x 128 ch x {proj, gate} ----
  const int fr = l & 15, fq = l >> 4;
  const int pair = w >> 1;
  const int prow0 = (w & 1) * 32;

  bf16x8 af[2][4];
  #pragma unroll
  for (int mi = 0; mi < 2; ++mi)
    #pragma unroll
    for (int ks = 0; ks < 4; ++ks)
      af[mi][ks] = *(const bf16x8*)&xn[prow0 + mi * 16 + fr][ks * 32 + fq * 8];

  const bf16* wpf = wt + (pair * 2) * 16384 + l * 8;      // proj frags
  const bf16* wgf = wt + (pair * 2 + 1) * 16384 + l * 8;  // gate frags
  const float* bp = pair ? bbp : bap;
  bf16* dst = pair ? b_t : a_t;

  #pragma unroll
  for (int nc = 0; nc < 2; ++nc) {
    // gate accumulators for 4 channel-tiles
    f32x4 aG[2][4];
    #pragma unroll
    for (int mi = 0; mi < 2; ++mi)
      #pragma unroll
      for (int n = 0; n < 4; ++n) aG[mi][n] = (f32x4){0.f, 0.f, 0.f, 0.f};
    #pragma unroll
    for (int n = 0; n < 4; ++n)
      #pragma unroll
      for (int ks = 0; ks < 4; ++ks) {
        const bf16x8 bv = *(const bf16x8*)(wgf + (((nc * 4 + n) * 4 + ks) << 9));
        aG[0][n] = mfma16(af[0][ks], bv, aG[0][n]);
        aG[1][n] = mfma16(af[1][ks], bv, aG[1][n]);
      }
    #pragma unroll
    for (int n = 0; n < 4; ++n) {
      const int ch = (nc * 4 + n) * 16 + fr;
      const float bias = bp[ch];
      f32x4 aP[2];
      aP[0] = (f32x4){0.f, 0.f, 0.f, 0.f};
      aP[1] = (f32x4){0.f, 0.f, 0.f, 0.f};
      #pragma unroll
      for (int ks = 0; ks < 4; ++ks) {
        const bf16x8 bv = *(const bf16x8*)(wpf + (((nc * 4 + n) * 4 + ks) << 9));
        aP[0] = mfma16(af[0][ks], bv, aP[0]);
        aP[1] = mfma16(af[1][ks], bv, aP[1]);
      }
      #pragma unroll
      for (int mi = 0; mi < 2; ++mi) {
        const int pb = prow0 + mi * 16 + fq * 4;
        const f32x4 m4 = *(const f32x4*)&ml[pb];
        bf16x4 pk;
        #pragma unroll
        for (int r = 0; r < 4; ++r) {
          const float sg = 1.f / (1.f + __expf(-aG[mi][n][r]));
          pk[r] = (bf16)((aP[mi][r] + bias) * sg * m4[r]);
        }
        *(bf16x4*)(dst + (size_t)ch * PTOT + p0 + pb) = pk;
      }
    }
  }
}

// ---------------------------------------------------------------------------
// k2: per-channel GEMM O_c = A_c(384x384) * B_c(384x384), 128x128 tile, BK=32.
// grid (9 tiles, 128 channels), 4 waves each own a 64x64 quadrant.
// Swapped-operand MFMA -> packed 8B stores along j.
// ---------------------------------------------------------------------------
__global__ __launch_bounds__(256) void k2_tri(
    const bf16* __restrict__ a_t, const bf16* __restrict__ b_t, bf16* __restrict__ o_t)
{
  __shared__ __align__(16) bf16 As[128][40];   // [i][k]
  __shared__ __align__(16) bf16 Bt[128][40];   // [j][k] (B transposed)
  const int t = threadIdx.x, l = t & 63, w = t >> 6;
  const int fr = l & 15, fq = l >> 4;
  const int ti = blockIdx.x;                   // 0..8
  const int c  = blockIdx.y;                   // channel
  const int i0 = (ti / 3) * 128, j0 = (ti % 3) * 128;
  const bf16* ap = a_t + (size_t)c * PTOT;
  const bf16* bp = b_t + (size_t)c * PTOT;
  const int wm = (w >> 1) * 64, wn = (w & 1) * 64;
  const int arow = t >> 2, aseg = t & 3;       // A staging
  const int bj = t & 127, bkh = (t >> 7) * 16; // B staging (transpose via registers)

  f32x4 acc[4][4];
  #pragma unroll
  for (int mi = 0; mi < 4; ++mi)
    #pragma unroll
    for (int ni = 0; ni < 4; ++ni) acc[mi][ni] = (f32x4){0.f, 0.f, 0.f, 0.f};

  for (int kt = 0; kt < 12; ++kt) {
    const int k0 = kt * 32;
    __syncthreads();
    // stage A [128][32]: rows contiguous in k
    #pragma unroll
    for (int rep = 0; rep < 2; ++rep) {
      const int row = arow + rep * 64;
      *(ivec4*)&As[row][aseg * 8] =
          *(const ivec4*)(ap + (size_t)(i0 + row) * N384 + k0 + aseg * 8);
    }
    // stage B^T [128][32]: strided-coalesced global reads (2B/lane, 128B/wave)
    bf16 rb[16] __attribute__((aligned(16)));
    #pragma unroll
    for (int kk = 0; kk < 16; ++kk)
      rb[kk] = bp[(size_t)(k0 + bkh + kk) * N384 + j0 + bj];
    *(ivec4*)&Bt[bj][bkh]     = *(const ivec4*)&rb[0];
    *(ivec4*)&Bt[bj][bkh + 8] = *(const ivec4*)&rb[8];
    __syncthreads();

    bf16x8 af[4], bfv[4];
    #pragma unroll
    for (int mi = 0; mi < 4; ++mi)
      af[mi] = *(const bf16x8*)&As[wm + mi * 16 + fr][fq * 8];
    #pragma unroll
    for (int ni = 0; ni < 4; ++ni)
      bfv[ni] = *(const bf16x8*)&Bt[wn + ni * 16 + fr][fq * 8];
    // swapped operands: D[jm][im] -> lane holds 4 consecutive j per (mi,ni)
    #pragma unroll
    for (int mi = 0; mi < 4; ++mi)
      #pragma unroll
      for (int ni = 0; ni < 4; ++ni)
        acc[mi][ni] = mfma16(bfv[ni], af[mi], acc[mi][ni]);
  }

  bf16* op = o_t + (size_t)c * PTOT;
  #pragma unroll
  for (int mi = 0; mi < 4; ++mi) {
    const int irow = i0 + wm + mi * 16 + fr;
    #pragma unroll
    for (int ni = 0; ni < 4; ++ni) {
      const int jcol = j0 + wn + ni * 16 + fq * 4;
      bf16x4 pk;
      #pragma unroll
      for (int r = 0; r < 4; ++r) pk[r] = (bf16)acc[mi][ni][r];
      *(bf16x4*)(op + (size_t)irow * N384 + jcol) = pk;
    }
  }
}

// ---------------------------------------------------------------------------
// k3: out = x + (o @ W_z + b_z). 64 positions/block, transpose-stage o.
// Swapped-operand MFMA -> f32x4 stores/reads along channel.
// W_z read in fragment order.
// ---------------------------------------------------------------------------
__global__ __launch_bounds__(256) void k3_out(
    const bf16* __restrict__ o_t, const bf16* __restrict__ wtz,
    const float* __restrict__ x, const float* __restrict__ bz,
    float* __restrict__ out)
{
  __shared__ __align__(16) bf16 Ao[64][136];
  const int t = threadIdx.x, l = t & 63, w = t >> 6;
  const int fr = l & 15, fq = l >> 4;
  const int p0 = blockIdx.x << 6;
  const int pos = t & 63, chh = (t >> 6) * 32;

  bf16 rb[32] __attribute__((aligned(16)));
  #pragma unroll
  for (int cc = 0; cc < 32; ++cc)
    rb[cc] = o_t[(size_t)(chh + cc) * PTOT + p0 + pos];
  #pragma unroll
  for (int q = 0; q < 4; ++q)
    *(ivec4*)&Ao[pos][chh + q * 8] = *(const ivec4*)&rb[q * 8];
  __syncthreads();

  bf16x8 af[4];
  #pragma unroll
  for (int ks = 0; ks < 4; ++ks)
    af[ks] = *(const bf16x8*)&Ao[w * 16 + fr][ks * 32 + fq * 8];

  const bf16* wzf = wtz + l * 8;
  f32x4 acc[8];
  #pragma unroll
  for (int n = 0; n < 8; ++n) acc[n] = (f32x4){0.f, 0.f, 0.f, 0.f};
  #pragma unroll
  for (int n = 0; n < 8; ++n)
    #pragma unroll
    for (int ks = 0; ks < 4; ++ks) {
      const bf16x8 bfv = *(const bf16x8*)(wzf + ((n * 4 + ks) << 9));
      // swapped: D rows = ch (wz m), cols = pos (af m)
      acc[n] = mfma16(bfv, af[ks], acc[n]);
    }

  const int pp = p0 + w * 16 + fr;
  #pragma unroll
  for (int n = 0; n < 8; ++n) {
    const int ch = n * 16 + fq * 4;
    const f32x4 b4 = *(const f32x4*)(bz + ch);
    const size_t idx = (size_t)pp * 128 + ch;
    const f32x4 x4 = *(const f32x4*)(x + idx);
    f32x4 o4;
    #pragma unroll
    for (int r = 0; r < 4; ++r) o4[r] = x4[r] + acc[n][r] + b4[r];
    *(f32x4*)(out + idx) = o4;
  }
}

// ---------------------------------------------------------------------------
extern "C" void kernel_launch(void* const* d_in, const int* in_sizes, int n_in,
                              void* d_out, int out_size, void* d_ws, size_t ws_size,
                              hipStream_t stream) {
  const float* x     = (const float*)d_in[0];
  const float* mask  = (const float*)d_in[1];
  const float* gamma = (const float*)d_in[2];
  const float* beta  = (const float*)d_in[3];
  const float* Wap   = (const float*)d_in[4];
  const float* bap   = (const float*)d_in[5];
  const float* Wag   = (const float*)d_in[6];
  const float* Wbp   = (const float*)d_in[7];
  const float* bbp   = (const float*)d_in[8];
  const float* Wbg   = (const float*)d_in[9];
  const float* Wz    = (const float*)d_in[10];
  const float* bz    = (const float*)d_in[11];

  char* ws = (char*)d_ws;
  bf16* wt  = (bf16*)ws;                         // 5*128*128 bf16 = 160KB
  bf16* a_t = (bf16*)(ws + 163840);              // [128][147456] bf16
  bf16* b_t = a_t + (size_t)128 * PTOT;
  bf16* o_t = b_t + (size_t)128 * PTOT;
  float* out = (float*)d_out;

  k_prep<<<5, 256, 0, stream>>>(Wap, Wag, Wbp, Wbg, Wz, wt);
  k1_ln_proj<<<2304, 256, 0, stream>>>(x, mask, gamma, beta, bap, bbp, wt, a_t, b_t);
  k2_tri<<<dim3(9, 128), 256, 0, stream>>>(a_t, b_t, o_t);
  k3_out<<<2304, 256, 0, stream>>>(o_t, wt + 4 * 16384, x, bz, out);
}

// Round 4
// 140.668 us; speedup vs baseline: 1.6165x; 1.1623x over previous
//
#include <hip/hip_runtime.h>

typedef __bf16 bf16;
typedef bf16 bf16x4 __attribute__((ext_vector_type(4)));
typedef bf16 bf16x8 __attribute__((ext_vector_type(8)));
typedef float f32x4 __attribute__((ext_vector_type(4)));
typedef int ivec4 __attribute__((ext_vector_type(4)));

#define PTOT 147456   // 384*384
#define N384 384

static __device__ __forceinline__ f32x4 mfma16(bf16x8 a, bf16x8 b, f32x4 c) {
  return __builtin_amdgcn_mfma_f32_16x16x32_bf16(a, b, c, 0, 0, 0);
}

// async global->LDS, 16B per lane: LDS dest = base + lane*16 (wave-uniform base)
static __device__ __forceinline__ void gload_lds16(const bf16* g, bf16* lds) {
  __builtin_amdgcn_global_load_lds(
      (const __attribute__((address_space(1))) void*)g,
      (__attribute__((address_space(3))) void*)lds, 16, 0, 0);
}

// ---------------------------------------------------------------------------
// k_prep: repack 5 weight matrices [128(in)][128(out)] f32 into per-lane MFMA
// fragment order (bf16): wf[m][ ((n*4+ks)*64 + lane)*8 + e ] =
//   W[k = ks*32 + (lane>>4)*8 + e][ch = n*16 + (lane&15)]
// slots: 0=W_a_p 1=W_a_g 2=W_b_p 3=W_b_g 4=W_z
// ---------------------------------------------------------------------------
__global__ __launch_bounds__(256) void k_prep(
    const float* __restrict__ w0, const float* __restrict__ w1,
    const float* __restrict__ w2, const float* __restrict__ w3,
    const float* __restrict__ w4, bf16* __restrict__ wt)
{
  const int m = blockIdx.x;
  const float* src = (m == 0) ? w0 : (m == 1) ? w1 : (m == 2) ? w2 : (m == 3) ? w3 : w4;
  bf16* dst = wt + m * 16384;
  for (int slot = threadIdx.x; slot < 2048; slot += 256) {
    const int l  = slot & 63;
    const int ks = (slot >> 6) & 3;
    const int n  = slot >> 8;
    const int ch = n * 16 + (l & 15);
    const int kb = ks * 32 + (l >> 4) * 8;
    bf16 tmp[8] __attribute__((aligned(16)));
    #pragma unroll
    for (int e = 0; e < 8; ++e)
      tmp[e] = (bf16)src[(size_t)(kb + e) * 128 + ch];
    *(ivec4*)(dst + slot * 8) = *(const ivec4*)tmp;
  }
}

// ---------------------------------------------------------------------------
// k1 v4: LayerNorm + 4 projections + register gating + mask.
// Weights staged to LDS via global_load_lds in 4 phases (32KB each, all 4
// matrices x 2 ch-tiles). xn in LDS with XOR swizzle (no pad, <=2-way).
// Block 256 = 4 waves, 64 positions. Wave w: pair=(w>>1), pos-half=(w&1).
// ---------------------------------------------------------------------------
__global__ __launch_bounds__(256) void k1_ln_proj(
    const float* __restrict__ x, const float* __restrict__ mask,
    const float* __restrict__ gamma, const float* __restrict__ beta,
    const float* __restrict__ bap, const float* __restrict__ bbp,
    const bf16* __restrict__ wt,
    bf16* __restrict__ a_t, bf16* __restrict__ b_t)
{
  __shared__ __align__(16) bf16 xn[64 * 128];        // 16 KB, XOR-swizzled
  __shared__ __align__(16) bf16 wl[4 * 2 * 4 * 512]; // 32 KB [mat][n2][ks][512]
  __shared__ float ml[64];

  const int t = threadIdx.x;
  const int l = t & 63;
  const int w = t >> 6;
  const int p0 = blockIdx.x << 6;
  const int fr = l & 15, fq = l >> 4;

  // ---- issue phase-0 weight staging (async; overlaps LN below) ----
  // wave w stages matrix w; frag (n,ks) at wt + w*16384 + ((n*4+ks)*64+l)*8
  const bf16* wsrc = wt + w * 16384 + l * 8;
  bf16* wdst = wl + w * 4096;
  #pragma unroll
  for (int n2 = 0; n2 < 2; ++n2)
    #pragma unroll
    for (int ks = 0; ks < 4; ++ks)
      gload_lds16(wsrc + ((n2 * 4 + ks) << 9), wdst + n2 * 2048 + ks * 512);

  if (t < 64) ml[t] = mask[p0 + t];

  // ---- LayerNorm: 2 rounds x 32 rows; thread -> row (t>>3), 16 channels ----
  const int csub = (t & 7) << 4;
  f32x4 g4[4], bt4[4];
  #pragma unroll
  for (int i = 0; i < 4; ++i) {
    g4[i]  = *(const f32x4*)(gamma + csub + i * 4);
    bt4[i] = *(const f32x4*)(beta  + csub + i * 4);
  }
  #pragma unroll
  for (int it = 0; it < 2; ++it) {
    const int row = (t >> 3) + it * 32;
    f32x4 v[4];
    const float* xb = x + (size_t)(p0 + row) * 128 + csub;
    #pragma unroll
    for (int i = 0; i < 4; ++i) v[i] = *(const f32x4*)(xb + i * 4);

    float s = 0.f, s2 = 0.f;
    #pragma unroll
    for (int i = 0; i < 4; ++i)
      #pragma unroll
      for (int j = 0; j < 4; ++j) { const float f = v[i][j]; s += f; s2 += f * f; }
    #pragma unroll
    for (int m = 1; m < 8; m <<= 1) {
      s  += __shfl_xor(s, m, 64);
      s2 += __shfl_xor(s2, m, 64);
    }
    const float mu = s * (1.f / 128.f);
    const float rs = rsqrtf(s2 * (1.f / 128.f) - mu * mu + 1e-5f);

    bf16x8 xv0, xv1;
    #pragma unroll
    for (int i = 0; i < 4; ++i)
      #pragma unroll
      for (int j = 0; j < 4; ++j) {
        const float f = (v[i][j] - mu) * rs * g4[i][j] + bt4[i][j];
        const int e = i * 4 + j;
        if (e < 8) xv0[e] = (bf16)f; else xv1[e - 8] = (bf16)f;
      }
    const int sw = (row & 7) << 3;
    *(bf16x8*)&xn[row * 128 + (csub ^ sw)]       = xv0;
    *(bf16x8*)&xn[row * 128 + ((csub + 8) ^ sw)] = xv1;
  }
  __syncthreads();   // xn visible + phase-0 weights landed (vmcnt drained)

  // ---- A fragments (swizzled reads, held in registers all kernel) ----
  const int pair = w >> 1;
  const int prow0 = (w & 1) * 32;
  bf16x8 af[2][4];
  #pragma unroll
  for (int mi = 0; mi < 2; ++mi)
    #pragma unroll
    for (int ks = 0; ks < 4; ++ks) {
      const int row = prow0 + mi * 16 + fr;
      af[mi][ks] = *(const bf16x8*)&xn[row * 128 + (((ks * 32 + fq * 8)) ^ ((fr & 7) << 3))];
    }

  const float* bp = pair ? bbp : bap;
  bf16* dst = pair ? b_t : a_t;
  const bf16* wpl = wl + (pair * 2) * 4096 + l * 8;      // proj frags (LDS)
  const bf16* wgl = wl + (pair * 2 + 1) * 4096 + l * 8;  // gate frags (LDS)

  #pragma unroll
  for (int p = 0; p < 4; ++p) {
    #pragma unroll
    for (int n2 = 0; n2 < 2; ++n2) {
      const int ch = (p * 2 + n2) * 16 + fr;
      f32x4 aG0 = (f32x4){0.f, 0.f, 0.f, 0.f};
      f32x4 aG1 = (f32x4){0.f, 0.f, 0.f, 0.f};
      #pragma unroll
      for (int ks = 0; ks < 4; ++ks) {
        const bf16x8 bv = *(const bf16x8*)(wgl + n2 * 2048 + ks * 512);
        aG0 = mfma16(af[0][ks], bv, aG0);
        aG1 = mfma16(af[1][ks], bv, aG1);
      }
      f32x4 aP0 = (f32x4){0.f, 0.f, 0.f, 0.f};
      f32x4 aP1 = (f32x4){0.f, 0.f, 0.f, 0.f};
      #pragma unroll
      for (int ks = 0; ks < 4; ++ks) {
        const bf16x8 bv = *(const bf16x8*)(wpl + n2 * 2048 + ks * 512);
        aP0 = mfma16(af[0][ks], bv, aP0);
        aP1 = mfma16(af[1][ks], bv, aP1);
      }
      const float bias = bp[ch];
      #pragma unroll
      for (int mi = 0; mi < 2; ++mi) {
        const f32x4 aG = mi ? aG1 : aG0;
        const f32x4 aP = mi ? aP1 : aP0;
        const int pb = prow0 + mi * 16 + fq * 4;
        const f32x4 m4 = *(const f32x4*)&ml[pb];
        bf16x4 pk;
        #pragma unroll
        for (int r = 0; r < 4; ++r) {
          const float sg = 1.f / (1.f + __expf(-aG[r]));
          pk[r] = (bf16)((aP[r] + bias) * sg * m4[r]);
        }
        *(bf16x4*)(dst + (size_t)ch * PTOT + p0 + pb) = pk;
      }
    }
    if (p < 3) {
      __syncthreads();   // all waves done reading phase p from wl
      #pragma unroll
      for (int n2 = 0; n2 < 2; ++n2)
        #pragma unroll
        for (int ks = 0; ks < 4; ++ks)
          gload_lds16(wsrc + ((((p + 1) * 2 + n2) * 4 + ks) << 9),
                      wdst + n2 * 2048 + ks * 512);
      __syncthreads();   // staging complete (vmcnt drained by barrier)
    }
  }
}

// ---------------------------------------------------------------------------
// k2: per-channel GEMM O_c = A_c(384x384) * B_c(384x384), 128x128 tile, BK=32.
// grid (9 tiles, 128 channels), 4 waves each own a 64x64 quadrant.
// Swapped-operand MFMA -> packed 8B stores along j.
// ---------------------------------------------------------------------------
__global__ __launch_bounds__(256) void k2_tri(
    const bf16* __restrict__ a_t, const bf16* __restrict__ b_t, bf16* __restrict__ o_t)
{
  __shared__ __align__(16) bf16 As[128][40];   // [i][k]
  __shared__ __align__(16) bf16 Bt[128][40];   // [j][k] (B transposed)
  const int t = threadIdx.x, l = t & 63, w = t >> 6;
  const int fr = l & 15, fq = l >> 4;
  const int ti = blockIdx.x;                   // 0..8
  const int c  = blockIdx.y;                   // channel
  const int i0 = (ti / 3) * 128, j0 = (ti % 3) * 128;
  const bf16* ap = a_t + (size_t)c * PTOT;
  const bf16* bp = b_t + (size_t)c * PTOT;
  const int wm = (w >> 1) * 64, wn = (w & 1) * 64;
  const int arow = t >> 2, aseg = t & 3;       // A staging
  const int bj = t & 127, bkh = (t >> 7) * 16; // B staging (transpose via registers)

  f32x4 acc[4][4];
  #pragma unroll
  for (int mi = 0; mi < 4; ++mi)
    #pragma unroll
    for (int ni = 0; ni < 4; ++ni) acc[mi][ni] = (f32x4){0.f, 0.f, 0.f, 0.f};

  for (int kt = 0; kt < 12; ++kt) {
    const int k0 = kt * 32;
    __syncthreads();
    // stage A [128][32]: rows contiguous in k
    #pragma unroll
    for (int rep = 0; rep < 2; ++rep) {
      const int row = arow + rep * 64;
      *(ivec4*)&As[row][aseg * 8] =
          *(const ivec4*)(ap + (size_t)(i0 + row) * N384 + k0 + aseg * 8);
    }
    // stage B^T [128][32]: strided-coalesced global reads (2B/lane, 128B/wave)
    bf16 rb[16] __attribute__((aligned(16)));
    #pragma unroll
    for (int kk = 0; kk < 16; ++kk)
      rb[kk] = bp[(size_t)(k0 + bkh + kk) * N384 + j0 + bj];
    *(ivec4*)&Bt[bj][bkh]     = *(const ivec4*)&rb[0];
    *(ivec4*)&Bt[bj][bkh + 8] = *(const ivec4*)&rb[8];
    __syncthreads();

    bf16x8 af[4], bfv[4];
    #pragma unroll
    for (int mi = 0; mi < 4; ++mi)
      af[mi] = *(const bf16x8*)&As[wm + mi * 16 + fr][fq * 8];
    #pragma unroll
    for (int ni = 0; ni < 4; ++ni)
      bfv[ni] = *(const bf16x8*)&Bt[wn + ni * 16 + fr][fq * 8];
    // swapped operands: D[jm][im] -> lane holds 4 consecutive j per (mi,ni)
    #pragma unroll
    for (int mi = 0; mi < 4; ++mi)
      #pragma unroll
      for (int ni = 0; ni < 4; ++ni)
        acc[mi][ni] = mfma16(bfv[ni], af[mi], acc[mi][ni]);
  }

  bf16* op = o_t + (size_t)c * PTOT;
  #pragma unroll
  for (int mi = 0; mi < 4; ++mi) {
    const int irow = i0 + wm + mi * 16 + fr;
    #pragma unroll
    for (int ni = 0; ni < 4; ++ni) {
      const int jcol = j0 + wn + ni * 16 + fq * 4;
      bf16x4 pk;
      #pragma unroll
      for (int r = 0; r < 4; ++r) pk[r] = (bf16)acc[mi][ni][r];
      *(bf16x4*)(op + (size_t)irow * N384 + jcol) = pk;
    }
  }
}

// ---------------------------------------------------------------------------
// k3: out = x + (o @ W_z + b_z). 64 positions/block, transpose-stage o.
// Swapped-operand MFMA -> f32x4 stores/reads along channel.
// ---------------------------------------------------------------------------
__global__ __launch_bounds__(256) void k3_out(
    const bf16* __restrict__ o_t, const bf16* __restrict__ wtz,
    const float* __restrict__ x, const float* __restrict__ bz,
    float* __restrict__ out)
{
  __shared__ __align__(16) bf16 Ao[64][136];
  const int t = threadIdx.x, l = t & 63, w = t >> 6;
  const int fr = l & 15, fq = l >> 4;
  const int p0 = blockIdx.x << 6;
  const int pos = t & 63, chh = (t >> 6) * 32;

  bf16 rb[32] __attribute__((aligned(16)));
  #pragma unroll
  for (int cc = 0; cc < 32; ++cc)
    rb[cc] = o_t[(size_t)(chh + cc) * PTOT + p0 + pos];
  #pragma unroll
  for (int q = 0; q < 4; ++q)
    *(ivec4*)&Ao[pos][chh + q * 8] = *(const ivec4*)&rb[q * 8];
  __syncthreads();

  bf16x8 af[4];
  #pragma unroll
  for (int ks = 0; ks < 4; ++ks)
    af[ks] = *(const bf16x8*)&Ao[w * 16 + fr][ks * 32 + fq * 8];

  const bf16* wzf = wtz + l * 8;
  f32x4 acc[8];
  #pragma unroll
  for (int n = 0; n < 8; ++n) acc[n] = (f32x4){0.f, 0.f, 0.f, 0.f};
  #pragma unroll
  for (int n = 0; n < 8; ++n)
    #pragma unroll
    for (int ks = 0; ks < 4; ++ks) {
      const bf16x8 bfv = *(const bf16x8*)(wzf + ((n * 4 + ks) << 9));
      // swapped: D rows = ch (wz m), cols = pos (af m)
      acc[n] = mfma16(bfv, af[ks], acc[n]);
    }

  const int pp = p0 + w * 16 + fr;
  #pragma unroll
  for (int n = 0; n < 8; ++n) {
    const int ch = n * 16 + fq * 4;
    const f32x4 b4 = *(const f32x4*)(bz + ch);
    const size_t idx = (size_t)pp * 128 + ch;
    const f32x4 x4 = *(const f32x4*)(x + idx);
    f32x4 o4;
    #pragma unroll
    for (int r = 0; r < 4; ++r) o4[r] = x4[r] + acc[n][r] + b4[r];
    *(f32x4*)(out + idx) = o4;
  }
}

// ---------------------------------------------------------------------------
extern "C" void kernel_launch(void* const* d_in, const int* in_sizes, int n_in,
                              void* d_out, int out_size, void* d_ws, size_t ws_size,
                              hipStream_t stream) {
  const float* x     = (const float*)d_in[0];
  const float* mask  = (const float*)d_in[1];
  const float* gamma = (const float*)d_in[2];
  const float* beta  = (const float*)d_in[3];
  const float* Wap   = (const float*)d_in[4];
  const float* bap   = (const float*)d_in[5];
  const float* Wag   = (const float*)d_in[6];
  const float* Wbp   = (const float*)d_in[7];
  const float* bbp   = (const float*)d_in[8];
  const float* Wbg   = (const float*)d_in[9];
  const float* Wz    = (const float*)d_in[10];
  const float* bz    = (const float*)d_in[11];

  char* ws = (char*)d_ws;
  bf16* wt  = (bf16*)ws;                         // 5*128*128 bf16 = 160KB
  bf16* a_t = (bf16*)(ws + 163840);              // [128][147456] bf16
  bf16* b_t = a_t + (size_t)128 * PTOT;
  bf16* o_t = b_t + (size_t)128 * PTOT;
  float* out = (float*)d_out;

  k_prep<<<5, 256, 0, stream>>>(Wap, Wag, Wbp, Wbg, Wz, wt);
  k1_ln_proj<<<2304, 256, 0, stream>>>(x, mask, gamma, beta, bap, bbp, wt, a_t, b_t);
  k2_tri<<<dim3(9, 128), 256, 0, stream>>>(a_t, b_t, o_t);
  k3_out<<<2304, 256, 0, stream>>>(o_t, wt + 4 * 16384, x, bz, out);
}